// Round 4
// baseline (614.589 us; speedup 1.0000x reference)
//
#include <hip/hip_runtime.h>

typedef __attribute__((ext_vector_type(8))) _Float16 half8;
typedef __attribute__((ext_vector_type(4))) _Float16 half4;
typedef __attribute__((ext_vector_type(4))) float f32x4;

#define N_SEQ 4096
#define HD_QK 96
#define HD_V  64
#define NHEADS 8
// Q pre-scale = (256/8)^-0.5 * log2(e) -> scores in log2 domain
#define QSCALE 0.25505545556f
#define ESHIFT 8.0f

__device__ inline half8 cvt8(float4 a, float4 b) {
    half8 h;
    h[0] = (_Float16)a.x; h[1] = (_Float16)a.y; h[2] = (_Float16)a.z; h[3] = (_Float16)a.w;
    h[4] = (_Float16)b.x; h[5] = (_Float16)b.y; h[6] = (_Float16)b.z; h[7] = (_Float16)b.w;
    return h;
}

// ---------------------------------------------------------------------------
// Pre-pass: transpose + cast: in f32 [R][C] -> out f16 [C][R]
// ---------------------------------------------------------------------------
__global__ __launch_bounds__(256) void transpose_cast(const float* __restrict__ in,
                                                      _Float16* __restrict__ out,
                                                      int R, int C) {
    __shared__ float tile[32][33];
    int tx = threadIdx.x & 31, ty = threadIdx.x >> 5;
    int c0 = blockIdx.x * 32, r0 = blockIdx.y * 32;
    for (int k = 0; k < 4; k++)
        tile[ty + 8 * k][tx] = in[(size_t)(r0 + ty + 8 * k) * C + c0 + tx];
    __syncthreads();
    for (int k = 0; k < 4; k++)
        out[(size_t)(c0 + ty + 8 * k) * R + r0 + tx] = (_Float16)tile[tx][ty + 8 * k];
}

// ---------------------------------------------------------------------------
// Fused projection GEMM: both projections in ONE launch.
// blockIdx.x < 12: qk[4096x768] @ Wqkt^T (N=1536) -> Qh (xQSCALE) / Kh
// else:            v_cls[4096x512] @ Wvt^T (N=512) -> Vtg[h][d][n]
// Tile 64m x 128n, BK=64; X staged f32->f16 (fused cast). 4 WG/CU.
// ---------------------------------------------------------------------------
__global__ __launch_bounds__(256) void proj_fused(
    const float* __restrict__ Xqk, const float* __restrict__ Xv,
    const _Float16* __restrict__ Wqkt, const _Float16* __restrict__ Wvt,
    _Float16* __restrict__ Qh, _Float16* __restrict__ Kh,
    _Float16* __restrict__ Vtg)
{
    __shared__ _Float16 smem[64 * 72 + 128 * 72];   // 27.6 KB
    _Float16 (*Xs)[72] = (_Float16 (*)[72])smem;
    _Float16 (*Ws)[72] = (_Float16 (*)[72])(smem + 64 * 72);

    const int t = threadIdx.x;
    const int lane = t & 63, wv = t >> 6;
    const int quad = lane >> 4, l15 = lane & 15;
    const bool qkmode = blockIdx.x < 12;
    const int n0 = qkmode ? blockIdx.x * 128 : (blockIdx.x - 12) * 128;
    const int row0 = blockIdx.y * 64;
    const int K = qkmode ? 768 : 512;
    const float* X = qkmode ? Xqk : Xv;
    const _Float16* Wt = qkmode ? Wqkt : Wvt;

    const int mB = (wv & 1) * 32, nB = (wv >> 1) * 64;
    const int xr = t >> 2, xc = (t & 3) * 16;
    const int wr = t >> 1, wc = (t & 1) * 32;

    const f32x4 fzero = {0.f, 0.f, 0.f, 0.f};
    f32x4 acc[2][4];
    for (int i = 0; i < 2; i++)
        for (int j = 0; j < 4; j++) acc[i][j] = fzero;

    for (int k0 = 0; k0 < K; k0 += 64) {
        __syncthreads();
        {   // X tile 64x64 f32 -> f16
            const float* xp = X + (size_t)(row0 + xr) * K + k0 + xc;
            float4 a0 = *(const float4*)xp;
            float4 a1 = *(const float4*)(xp + 4);
            float4 a2 = *(const float4*)(xp + 8);
            float4 a3 = *(const float4*)(xp + 12);
            *(half8*)&Xs[xr][xc]     = cvt8(a0, a1);
            *(half8*)&Xs[xr][xc + 8] = cvt8(a2, a3);
        }
        {   // W tile 128x64 f16
            const _Float16* wp = Wt + (size_t)(n0 + wr) * K + k0 + wc;
            *(half8*)&Ws[wr][wc]      = *(const half8*)wp;
            *(half8*)&Ws[wr][wc + 8]  = *(const half8*)(wp + 8);
            *(half8*)&Ws[wr][wc + 16] = *(const half8*)(wp + 16);
            *(half8*)&Ws[wr][wc + 24] = *(const half8*)(wp + 24);
        }
        __syncthreads();
        for (int c = 0; c < 2; c++) {
            half8 af[2], bf[4];
            for (int i = 0; i < 2; i++)
                af[i] = *(const half8*)&Xs[mB + 16 * i + l15][c * 32 + quad * 8];
            for (int j = 0; j < 4; j++)
                bf[j] = *(const half8*)&Ws[nB + 16 * j + l15][c * 32 + quad * 8];
            for (int i = 0; i < 2; i++)
                for (int j = 0; j < 4; j++)
                    acc[i][j] = __builtin_amdgcn_mfma_f32_16x16x32_f16(af[i], bf[j], acc[i][j], 0, 0, 0);
        }
    }

    // epilogue: stage 64x128 C tile (f16, scaled) then coalesced stores
    __syncthreads();
    _Float16 (*Ct)[136] = (_Float16 (*)[136])smem;   // 64*136*2 = 17.4 KB
    for (int j = 0; j < 4; j++) {
        int col = n0 + nB + 16 * j + l15;
        float scl = (qkmode && col < 768) ? QSCALE : 1.0f;
        for (int i = 0; i < 2; i++)
            for (int r = 0; r < 4; r++)
                Ct[mB + 16 * i + quad * 4 + r][nB + 16 * j + l15] =
                    (_Float16)(acc[i][j][r] * scl);
    }
    __syncthreads();

    if (qkmode) {
        for (int e = 0; e < 4; e++) {
            int id = e * 256 + t;
            int row = id >> 4, cc = id & 15;
            int col = n0 + cc * 8;
            int w = col >= 768 ? 1 : 0;
            int rem = col - w * 768;
            int h = rem / 96, d = rem - h * 96;
            _Float16* dst = w ? Kh : Qh;
            *(half8*)&dst[((size_t)h * N_SEQ + row0 + row) * HD_QK + d] =
                *(const half8*)&Ct[row][cc * 8];
        }
    } else {
        for (int e = 0; e < 2; e++) {
            int id = e * 256 + t;
            int col = id >> 2, rc = id & 3;
            int c = n0 + col;
            int h = c >> 6, d = c & 63;
            half8 v0, v1;
            for (int k = 0; k < 8; k++) {
                v0[k] = Ct[rc * 16 + k][col];
                v1[k] = Ct[rc * 16 + 8 + k][col];
            }
            _Float16* dst = &Vtg[((size_t)h * HD_V + d) * N_SEQ + row0 + rc * 16];
            *(half8*)dst = v0;
            *(half8*)(dst + 8) = v1;
        }
    }
}

// ---------------------------------------------------------------------------
// Flash attention, key-sliced waves + split-K by 2 (grid.z).
// Wave w owns keys 16w..16w+15 of each 64-key block; blockIdx.z picks which
// 32 of the 64 key-blocks. No max tracking (p = exp2(s'-8), exact shift).
// End: pairwise f32 LDS combine of 4 waves, write partial (O,l,m) to ws.
// ---------------------------------------------------------------------------
__global__ __launch_bounds__(256, 4) void flash_attn(
    const _Float16* __restrict__ Qh, const _Float16* __restrict__ Kh,
    const _Float16* __restrict__ Vtg, const float* __restrict__ masks,
    float* __restrict__ Ows, float* __restrict__ Lws, float* __restrict__ Mws)
{
    __shared__ __align__(16) float Ob[2][64][68];   // 34.8 KB
    __shared__ float Lb[2][64];
    __shared__ float Mb[2][64];

    const int t = threadIdx.x;
    const int lane = t & 63, w = t >> 6;
    const int quad = lane >> 4, l15 = lane & 15;
    const int head = blockIdx.y;
    const int q0 = blockIdx.x * 64;
    const int z = blockIdx.z;
    const int kb0 = z * 32, kbE = kb0 + 32;

    // Q fragments (B-operand of 16x16x32): per q-tile nt
    half8 qf[3][4];
    for (int nt = 0; nt < 4; nt++) {
        const _Float16* qp = Qh + ((size_t)head * N_SEQ + q0 + 16 * nt + l15) * HD_QK + 8 * quad;
        for (int c = 0; c < 3; c++)
            qf[c][nt] = *(const half8*)(qp + 32 * c);
    }

    const _Float16* kbase = Kh + ((size_t)head * N_SEQ + 16 * w + l15) * HD_QK + 8 * quad;
    const _Float16* vbase = Vtg + ((size_t)head * HD_V + l15) * N_SEQ + 16 * w + 4 * quad;
    const float*    mbase = masks + (size_t)(q0 + l15) * N_SEQ + 16 * w + 4 * quad;

    const f32x4 fzero = {0.f, 0.f, 0.f, 0.f};
    f32x4 oacc[4][4];
    for (int nt = 0; nt < 4; nt++)
        for (int v = 0; v < 4; v++) oacc[nt][v] = fzero;
    float lsum[4] = {0.f, 0.f, 0.f, 0.f};
    float msum[4] = {0.f, 0.f, 0.f, 0.f};

    half8 kf[2][3];
    half4 vf[2][4];
    float4 mf[2][4];
    for (int c = 0; c < 3; c++) kf[0][c] = *(const half8*)(kbase + (size_t)kb0 * 64 * HD_QK + 32 * c);
    for (int v = 0; v < 4; v++) vf[0][v] = *(const half4*)(vbase + (size_t)(16 * v) * N_SEQ + kb0 * 64);
    for (int nt = 0; nt < 4; nt++) mf[0][nt] = *(const float4*)(mbase + (size_t)(16 * nt) * N_SEQ + kb0 * 64);

#pragma unroll 2
    for (int kb = kb0; kb < kbE; kb++) {
        const int cu = kb & 1, nx = cu ^ 1;
        {   // prefetch kb+1 (clamped within range)
            int kn = (kb + 1 < kbE) ? kb + 1 : kb;
            const _Float16* kp = kbase + (size_t)kn * 64 * HD_QK;
            for (int c = 0; c < 3; c++) kf[nx][c] = *(const half8*)(kp + 32 * c);
            const _Float16* vp = vbase + kn * 64;
            for (int v = 0; v < 4; v++) vf[nx][v] = *(const half4*)(vp + (size_t)(16 * v) * N_SEQ);
            const float* mp = mbase + kn * 64;
            for (int nt = 0; nt < 4; nt++) mf[nx][nt] = *(const float4*)(mp + (size_t)(16 * nt) * N_SEQ);
        }

        // S^T = K Q^T
        f32x4 sT[4];
        for (int nt = 0; nt < 4; nt++) sT[nt] = fzero;
        for (int c = 0; c < 3; c++)
            for (int nt = 0; nt < 4; nt++)
                sT[nt] = __builtin_amdgcn_mfma_f32_16x16x32_f16(kf[cu][c], qf[c][nt], sT[nt], 0, 0, 0);

        // p = exp2(s-8); accumulate l, masksum; build PV A-frags
        half4 af[4];
        for (int nt = 0; nt < 4; nt++) {
            float4 mv = mf[cu][nt];
            float p0 = exp2f(sT[nt][0] - ESHIFT);
            float p1 = exp2f(sT[nt][1] - ESHIFT);
            float p2 = exp2f(sT[nt][2] - ESHIFT);
            float p3 = exp2f(sT[nt][3] - ESHIFT);
            lsum[nt] += (p0 + p1) + (p2 + p3);
            msum[nt] += (mv.x + mv.y) + (mv.z + mv.w);
            half4 a;
            a[0] = (_Float16)(p0 * mv.x);
            a[1] = (_Float16)(p1 * mv.y);
            a[2] = (_Float16)(p2 * mv.z);
            a[3] = (_Float16)(p3 * mv.w);
            af[nt] = a;
        }

        for (int nt = 0; nt < 4; nt++)
            for (int v = 0; v < 4; v++)
                oacc[nt][v] = __builtin_amdgcn_mfma_f32_16x16x16f16(af[nt], vf[cu][v], oacc[nt][v], 0, 0, 0);
    }

    // ---- reduce l/m across quads (every lane ends with full value)
    for (int nt = 0; nt < 4; nt++) {
        lsum[nt] += __shfl_xor(lsum[nt], 16);
        lsum[nt] += __shfl_xor(lsum[nt], 32);
        msum[nt] += __shfl_xor(msum[nt], 16);
        msum[nt] += __shfl_xor(msum[nt], 32);
    }

    // ---- pairwise combine: waves {0,1} -> Ob[0], {2,3} -> Ob[1]
    if (w & 1) {
        for (int nt = 0; nt < 4; nt++) {
            for (int v = 0; v < 4; v++)
                for (int r = 0; r < 4; r++)
                    Ob[w >> 1][16 * nt + 4 * quad + r][16 * v + l15] = oacc[nt][v][r];
            if (quad == 0) {
                Lb[w >> 1][16 * nt + l15] = lsum[nt];
                Mb[w >> 1][16 * nt + l15] = msum[nt];
            }
        }
    }
    __syncthreads();
    if (!(w & 1)) {
        for (int nt = 0; nt < 4; nt++) {
            for (int v = 0; v < 4; v++)
                for (int r = 0; r < 4; r++)
                    Ob[w >> 1][16 * nt + 4 * quad + r][16 * v + l15] += oacc[nt][v][r];
            if (quad == 0) {
                Lb[w >> 1][16 * nt + l15] += lsum[nt];
                Mb[w >> 1][16 * nt + l15] += msum[nt];
            }
        }
    }
    __syncthreads();

    // ---- final sum of the two buffers -> ws (coalesced)
    {
        int row = t >> 2, c0 = (t & 3) * 16;
        float* obase = Ows + (size_t)z * N_SEQ * 512 + (size_t)(q0 + row) * 512 + head * HD_V + c0;
        for (int g = 0; g < 4; g++) {
            f32x4 s = *(const f32x4*)&Ob[0][row][c0 + 4 * g];
            s += *(const f32x4*)&Ob[1][row][c0 + 4 * g];
            *(f32x4*)(obase + 4 * g) = s;
        }
        if (t < 64)
            Lws[(size_t)z * NHEADS * N_SEQ + head * N_SEQ + q0 + t] = Lb[0][t] + Lb[1][t];
        else if (t < 128)
            Mws[(size_t)z * NHEADS * N_SEQ + head * N_SEQ + q0 + (t - 64)] = Mb[0][t - 64] + Mb[1][t - 64];
    }
}

// ---------------------------------------------------------------------------
// Finalize: out = (O0+O1) / ((l0+l1) * H * (m0+m1))
// ---------------------------------------------------------------------------
__global__ __launch_bounds__(256) void finalize(
    const float* __restrict__ Ows, const float* __restrict__ Lws,
    const float* __restrict__ Mws, float* __restrict__ out)
{
    size_t o = ((size_t)blockIdx.x * 256 + threadIdx.x) * 4;
    int q = (int)(o >> 9);
    int head = (int)((o & 511) >> 6);
    f32x4 a = *(const f32x4*)(Ows + o);
    a += *(const f32x4*)(Ows + (size_t)N_SEQ * 512 + o);
    float l = Lws[head * N_SEQ + q] + Lws[NHEADS * N_SEQ + head * N_SEQ + q];
    float m = Mws[head * N_SEQ + q] + Mws[NHEADS * N_SEQ + head * N_SEQ + q];
    *(f32x4*)(out + o) = a * (1.0f / (l * (float)NHEADS * m));
}

extern "C" void kernel_launch(void* const* d_in, const int* in_sizes, int n_in,
                              void* d_out, int out_size, void* d_ws, size_t ws_size,
                              hipStream_t stream) {
    const float* qk    = (const float*)d_in[0];
    const float* v_cls = (const float*)d_in[1];
    const float* masks = (const float*)d_in[2];
    const float* W_qk  = (const float*)d_in[3];
    const float* W_v   = (const float*)d_in[4];
    float* out = (float*)d_out;

    char* wsp = (char*)d_ws;
    size_t off = 0;
    auto allocH = [&](size_t elems) { _Float16* p = (_Float16*)(wsp + off); off += elems * 2; return p; };
    _Float16* Wqkt = allocH((size_t)1536 * 768);
    _Float16* Wvt  = allocH((size_t)512 * 512);
    _Float16* Qh   = allocH((size_t)NHEADS * N_SEQ * HD_QK);
    _Float16* Kh   = allocH((size_t)NHEADS * N_SEQ * HD_QK);
    _Float16* Vtg  = allocH((size_t)NHEADS * HD_V * N_SEQ);
    auto allocF = [&](size_t elems) { float* p = (float*)(wsp + off); off += elems * 4; return p; };
    float* Ows = allocF((size_t)2 * N_SEQ * 512);
    float* Lws = allocF((size_t)2 * NHEADS * N_SEQ);
    float* Mws = allocF((size_t)2 * NHEADS * N_SEQ);
    (void)ws_size;

    dim3 blk(256);
    transpose_cast<<<dim3(1536 / 32, 768 / 32), blk, 0, stream>>>(W_qk, Wqkt, 768, 1536);
    transpose_cast<<<dim3(512 / 32, 512 / 32), blk, 0, stream>>>(W_v, Wvt, 512, 512);

    proj_fused<<<dim3(16, N_SEQ / 64), blk, 0, stream>>>(
        qk, v_cls, Wqkt, Wvt, Qh, Kh, Vtg);

    flash_attn<<<dim3(N_SEQ / 64, NHEADS, 2), blk, 0, stream>>>(
        Qh, Kh, Vtg, masks, Ows, Lws, Mws);

    finalize<<<dim3((N_SEQ * 512) / (256 * 4)), blk, 0, stream>>>(
        Ows, Lws, Mws, out);
}

// Round 5
// 367.324 us; speedup vs baseline: 1.6732x; 1.6732x over previous
//
#include <hip/hip_runtime.h>

typedef __attribute__((ext_vector_type(8))) _Float16 half8;
typedef __attribute__((ext_vector_type(4))) _Float16 half4;
typedef __attribute__((ext_vector_type(4))) float f32x4;

#define N_SEQ 4096
#define HD_QK 96
#define HD_V  64
#define NHEADS 8
// Q pre-scale = (256/8)^-0.5 * log2(e) -> scores in log2 domain
#define QSCALE 0.25505545556f
#define ESHIFT 8.0f

__device__ inline half8 cvt8(float4 a, float4 b) {
    half8 h;
    h[0] = (_Float16)a.x; h[1] = (_Float16)a.y; h[2] = (_Float16)a.z; h[3] = (_Float16)a.w;
    h[4] = (_Float16)b.x; h[5] = (_Float16)b.y; h[6] = (_Float16)b.z; h[7] = (_Float16)b.w;
    return h;
}

__device__ inline void cast_blk(const float* __restrict__ in, _Float16* __restrict__ out,
                                int blk, int t) {
    size_t i = ((size_t)blk * 256 + t) * 8;
    float4 a = *(const float4*)(in + i);
    float4 b = *(const float4*)(in + i + 4);
    *(half8*)(out + i) = cvt8(a, b);
}

// ---------------------------------------------------------------------------
// Prep (one launch): cast qk / v_cls / masks to f16; transpose+cast W_qk, W_v.
// Block ranges: [0,1536) qk | [1536,2560) v_cls | [2560,3712) W_qk^T |
//               [3712,3968) W_v^T | [3968,12160) masks (only if f16 path)
// ---------------------------------------------------------------------------
__global__ __launch_bounds__(256) void prep(
    const float* __restrict__ qk, const float* __restrict__ v_cls,
    const float* __restrict__ masks, const float* __restrict__ W_qk,
    const float* __restrict__ W_v,
    _Float16* __restrict__ Xh, _Float16* __restrict__ Vch,
    _Float16* __restrict__ Mh, _Float16* __restrict__ Wqkt,
    _Float16* __restrict__ Wvt)
{
    __shared__ float tile[32][33];
    const int bx = blockIdx.x, t = threadIdx.x;
    if (bx < 1536) {
        cast_blk(qk, Xh, bx, t);
    } else if (bx < 2560) {
        cast_blk(v_cls, Vch, bx - 1536, t);
    } else if (bx < 3968) {
        const bool big = bx < 3712;
        const int id = big ? bx - 2560 : bx - 3712;
        const int nx = big ? 48 : 16;
        const int C = big ? 1536 : 512, R = big ? 768 : 512;
        const float* in = big ? W_qk : W_v;
        _Float16* out = big ? Wqkt : Wvt;
        int cx = id % nx, cy = id / nx;
        int tx = t & 31, ty = t >> 5;
        int c0 = cx * 32, r0 = cy * 32;
        for (int k = 0; k < 4; k++)
            tile[ty + 8 * k][tx] = in[(size_t)(r0 + ty + 8 * k) * C + c0 + tx];
        __syncthreads();
        for (int k = 0; k < 4; k++)
            out[(size_t)(c0 + ty + 8 * k) * R + r0 + tx] = (_Float16)tile[tx][ty + 8 * k];
    } else {
        cast_blk(masks, Mh, bx - 3968, t);
    }
}

// ---------------------------------------------------------------------------
// Fused projection GEMM (f16 in): blockIdx.x<12: Xh@Wqkt^T -> Qh(xQSCALE)/Kh
// else Vch@Wvt^T -> Vtg[h][d][n]. Tile 64m x 128n, BK=64. x-fastest dispatch
// keeps the whole W panel L2-resident.
// ---------------------------------------------------------------------------
__global__ __launch_bounds__(256) void proj_fused(
    const _Float16* __restrict__ Xh, const _Float16* __restrict__ Vch,
    const _Float16* __restrict__ Wqkt, const _Float16* __restrict__ Wvt,
    _Float16* __restrict__ Qh, _Float16* __restrict__ Kh,
    _Float16* __restrict__ Vtg)
{
    __shared__ _Float16 smem[64 * 72 + 128 * 72];
    _Float16 (*Xs)[72] = (_Float16 (*)[72])smem;
    _Float16 (*Ws)[72] = (_Float16 (*)[72])(smem + 64 * 72);

    const int t = threadIdx.x;
    const int lane = t & 63, wv = t >> 6;
    const int quad = lane >> 4, l15 = lane & 15;
    const bool qkmode = blockIdx.x < 12;
    const int n0 = qkmode ? blockIdx.x * 128 : (blockIdx.x - 12) * 128;
    const int row0 = blockIdx.y * 64;
    const int K = qkmode ? 768 : 512;
    const _Float16* X = qkmode ? Xh : Vch;
    const _Float16* Wt = qkmode ? Wqkt : Wvt;

    const int mB = (wv & 1) * 32, nB = (wv >> 1) * 64;
    const int xr = t >> 2, xc = (t & 3) * 16;
    const int wr = t >> 1, wc = (t & 1) * 32;

    const f32x4 fzero = {0.f, 0.f, 0.f, 0.f};
    f32x4 acc[2][4];
    for (int i = 0; i < 2; i++)
        for (int j = 0; j < 4; j++) acc[i][j] = fzero;

    for (int k0 = 0; k0 < K; k0 += 64) {
        __syncthreads();
        {   // X tile 64x64 f16
            const _Float16* xp = X + (size_t)(row0 + xr) * K + k0 + xc;
            *(half8*)&Xs[xr][xc]     = *(const half8*)xp;
            *(half8*)&Xs[xr][xc + 8] = *(const half8*)(xp + 8);
        }
        {   // W tile 128x64 f16
            const _Float16* wp = Wt + (size_t)(n0 + wr) * K + k0 + wc;
            *(half8*)&Ws[wr][wc]      = *(const half8*)wp;
            *(half8*)&Ws[wr][wc + 8]  = *(const half8*)(wp + 8);
            *(half8*)&Ws[wr][wc + 16] = *(const half8*)(wp + 16);
            *(half8*)&Ws[wr][wc + 24] = *(const half8*)(wp + 24);
        }
        __syncthreads();
        for (int c = 0; c < 2; c++) {
            half8 af[2], bf[4];
            for (int i = 0; i < 2; i++)
                af[i] = *(const half8*)&Xs[mB + 16 * i + l15][c * 32 + quad * 8];
            for (int j = 0; j < 4; j++)
                bf[j] = *(const half8*)&Ws[nB + 16 * j + l15][c * 32 + quad * 8];
            for (int i = 0; i < 2; i++)
                for (int j = 0; j < 4; j++)
                    acc[i][j] = __builtin_amdgcn_mfma_f32_16x16x32_f16(af[i], bf[j], acc[i][j], 0, 0, 0);
        }
    }

    __syncthreads();
    _Float16 (*Ct)[136] = (_Float16 (*)[136])smem;
    for (int j = 0; j < 4; j++) {
        int col = n0 + nB + 16 * j + l15;
        float scl = (qkmode && col < 768) ? QSCALE : 1.0f;
        for (int i = 0; i < 2; i++)
            for (int r = 0; r < 4; r++)
                Ct[mB + 16 * i + quad * 4 + r][nB + 16 * j + l15] =
                    (_Float16)(acc[i][j][r] * scl);
    }
    __syncthreads();

    if (qkmode) {
        for (int e = 0; e < 4; e++) {
            int id = e * 256 + t;
            int row = id >> 4, cc = id & 15;
            int col = n0 + cc * 8;
            int w = col >= 768 ? 1 : 0;
            int rem = col - w * 768;
            int h = rem / 96, d = rem - h * 96;
            _Float16* dst = w ? Kh : Qh;
            *(half8*)&dst[((size_t)h * N_SEQ + row0 + row) * HD_QK + d] =
                *(const half8*)&Ct[row][cc * 8];
        }
    } else {
        for (int e = 0; e < 2; e++) {
            int id = e * 256 + t;
            int col = id >> 2, rc = id & 3;
            int c = n0 + col;
            int h = c >> 6, d = c & 63;
            half8 v0, v1;
            for (int k = 0; k < 8; k++) {
                v0[k] = Ct[rc * 16 + k][col];
                v1[k] = Ct[rc * 16 + 8 + k][col];
            }
            _Float16* dst = &Vtg[((size_t)h * HD_V + d) * N_SEQ + row0 + rc * 16];
            *(half8*)dst = v0;
            *(half8*)(dst + 8) = v1;
        }
    }
}

// ---------------------------------------------------------------------------
// Flash attention: key-sliced waves, split-K z=2, XCD-pinned heads.
// head = bx&7 (round-robin dispatch pins one head per XCD -> K/V L2-resident).
// Single-buffered software-pipelined loads (reload right after last use).
// ---------------------------------------------------------------------------
__device__ inline float4 mask_to_f4(float4 v) { return v; }
__device__ inline float4 mask_to_f4(half4 v) {
    return float4{(float)v[0], (float)v[1], (float)v[2], (float)v[3]};
}
template<typename T> struct MaskVec;
template<> struct MaskVec<float>    { using type = float4; };
template<> struct MaskVec<_Float16> { using type = half4; };

template<typename MT>
__global__ __launch_bounds__(256, 3) void flash_attn(
    const _Float16* __restrict__ Qh, const _Float16* __restrict__ Kh,
    const _Float16* __restrict__ Vtg, const MT* __restrict__ masks,
    float* __restrict__ Ows, float* __restrict__ Lws, float* __restrict__ Mws)
{
    __shared__ __align__(16) float Ob[2][64][68];
    __shared__ float Lb[2][64];
    __shared__ float Mb[2][64];

    const int t = threadIdx.x;
    const int lane = t & 63, w = t >> 6;
    const int quad = lane >> 4, l15 = lane & 15;
    const int bx = blockIdx.x;
    const int head = bx & 7;
    const int rest = bx >> 3;
    const int q0 = (rest & 63) * 64;
    const int z = rest >> 6;
    const int kb0 = z * 32, kbE = kb0 + 32;

    half8 qf[3][4];
    for (int nt = 0; nt < 4; nt++) {
        const _Float16* qp = Qh + ((size_t)head * N_SEQ + q0 + 16 * nt + l15) * HD_QK + 8 * quad;
        for (int c = 0; c < 3; c++)
            qf[c][nt] = *(const half8*)(qp + 32 * c);
    }

    const _Float16* kbase = Kh + ((size_t)head * N_SEQ + 16 * w + l15) * HD_QK + 8 * quad;
    const _Float16* vbase = Vtg + ((size_t)head * HD_V + l15) * N_SEQ + 16 * w + 4 * quad;
    const MT*       mbase = masks + (size_t)(q0 + l15) * N_SEQ + 16 * w + 4 * quad;
    using MV = typename MaskVec<MT>::type;

    const f32x4 fzero = {0.f, 0.f, 0.f, 0.f};
    f32x4 oacc[4][4];
    for (int nt = 0; nt < 4; nt++)
        for (int v = 0; v < 4; v++) oacc[nt][v] = fzero;
    float lsum[4] = {0.f, 0.f, 0.f, 0.f};
    float msum[4] = {0.f, 0.f, 0.f, 0.f};

    half8 kf[3];
    half4 vf[4];
    MV mf[4];
    {
        const _Float16* kp = kbase + (size_t)kb0 * 64 * HD_QK;
        for (int c = 0; c < 3; c++) kf[c] = *(const half8*)(kp + 32 * c);
        const _Float16* vp = vbase + kb0 * 64;
        for (int v = 0; v < 4; v++) vf[v] = *(const half4*)(vp + (size_t)(16 * v) * N_SEQ);
        const MT* mp = mbase + (size_t)kb0 * 64;
        for (int nt = 0; nt < 4; nt++) mf[nt] = *(const MV*)(mp + (size_t)(16 * nt) * N_SEQ);
    }

    for (int kb = kb0; kb < kbE; kb++) {
        const int kn = (kb + 1 < kbE) ? kb + 1 : kb;

        // S^T = K Q^T (uses kf)
        f32x4 sT[4];
        for (int nt = 0; nt < 4; nt++) sT[nt] = fzero;
        for (int c = 0; c < 3; c++)
            for (int nt = 0; nt < 4; nt++)
                sT[nt] = __builtin_amdgcn_mfma_f32_16x16x32_f16(kf[c], qf[c][nt], sT[nt], 0, 0, 0);
        {   // reload kf for next iter (pipeline: consumed above)
            const _Float16* kp = kbase + (size_t)kn * 64 * HD_QK;
            for (int c = 0; c < 3; c++) kf[c] = *(const half8*)(kp + 32 * c);
        }

        // softmax + mask (uses mf)
        half4 af[4];
        for (int nt = 0; nt < 4; nt++) {
            float4 mv = mask_to_f4(mf[nt]);
            float p0 = exp2f(sT[nt][0] - ESHIFT);
            float p1 = exp2f(sT[nt][1] - ESHIFT);
            float p2 = exp2f(sT[nt][2] - ESHIFT);
            float p3 = exp2f(sT[nt][3] - ESHIFT);
            lsum[nt] += (p0 + p1) + (p2 + p3);
            msum[nt] += (mv.x + mv.y) + (mv.z + mv.w);
            half4 a;
            a[0] = (_Float16)(p0 * mv.x);
            a[1] = (_Float16)(p1 * mv.y);
            a[2] = (_Float16)(p2 * mv.z);
            a[3] = (_Float16)(p3 * mv.w);
            af[nt] = a;
        }
        {   // reload mf
            const MT* mp = mbase + (size_t)kn * 64;
            for (int nt = 0; nt < 4; nt++) mf[nt] = *(const MV*)(mp + (size_t)(16 * nt) * N_SEQ);
        }

        // O += P V (uses vf)
        for (int nt = 0; nt < 4; nt++)
            for (int v = 0; v < 4; v++)
                oacc[nt][v] = __builtin_amdgcn_mfma_f32_16x16x16f16(af[nt], vf[v], oacc[nt][v], 0, 0, 0);
        {   // reload vf
            const _Float16* vp = vbase + kn * 64;
            for (int v = 0; v < 4; v++) vf[v] = *(const half4*)(vp + (size_t)(16 * v) * N_SEQ);
        }
    }

    for (int nt = 0; nt < 4; nt++) {
        lsum[nt] += __shfl_xor(lsum[nt], 16);
        lsum[nt] += __shfl_xor(lsum[nt], 32);
        msum[nt] += __shfl_xor(msum[nt], 16);
        msum[nt] += __shfl_xor(msum[nt], 32);
    }

    if (w & 1) {
        for (int nt = 0; nt < 4; nt++) {
            for (int v = 0; v < 4; v++)
                for (int r = 0; r < 4; r++)
                    Ob[w >> 1][16 * nt + 4 * quad + r][16 * v + l15] = oacc[nt][v][r];
            if (quad == 0) {
                Lb[w >> 1][16 * nt + l15] = lsum[nt];
                Mb[w >> 1][16 * nt + l15] = msum[nt];
            }
        }
    }
    __syncthreads();
    if (!(w & 1)) {
        for (int nt = 0; nt < 4; nt++) {
            for (int v = 0; v < 4; v++)
                for (int r = 0; r < 4; r++)
                    Ob[w >> 1][16 * nt + 4 * quad + r][16 * v + l15] += oacc[nt][v][r];
            if (quad == 0) {
                Lb[w >> 1][16 * nt + l15] += lsum[nt];
                Mb[w >> 1][16 * nt + l15] += msum[nt];
            }
        }
    }
    __syncthreads();

    {
        int row = t >> 2, c0 = (t & 3) * 16;
        float* obase = Ows + (size_t)z * N_SEQ * 512 + (size_t)(q0 + row) * 512 + head * HD_V + c0;
        for (int g = 0; g < 4; g++) {
            f32x4 s = *(const f32x4*)&Ob[0][row][c0 + 4 * g];
            s += *(const f32x4*)&Ob[1][row][c0 + 4 * g];
            *(f32x4*)(obase + 4 * g) = s;
        }
        if (t < 64)
            Lws[(size_t)z * NHEADS * N_SEQ + head * N_SEQ + q0 + t] = Lb[0][t] + Lb[1][t];
        else if (t < 128)
            Mws[(size_t)z * NHEADS * N_SEQ + head * N_SEQ + q0 + (t - 64)] = Mb[0][t - 64] + Mb[1][t - 64];
    }
}

// ---------------------------------------------------------------------------
// Finalize: out = (O0+O1) / ((l0+l1) * H * (m0+m1))
// ---------------------------------------------------------------------------
__global__ __launch_bounds__(256) void finalize(
    const float* __restrict__ Ows, const float* __restrict__ Lws,
    const float* __restrict__ Mws, float* __restrict__ out)
{
    size_t o = ((size_t)blockIdx.x * 256 + threadIdx.x) * 4;
    int q = (int)(o >> 9);
    int head = (int)((o & 511) >> 6);
    f32x4 a = *(const f32x4*)(Ows + o);
    a += *(const f32x4*)(Ows + (size_t)N_SEQ * 512 + o);
    float l = Lws[head * N_SEQ + q] + Lws[NHEADS * N_SEQ + head * N_SEQ + q];
    float m = Mws[head * N_SEQ + q] + Mws[NHEADS * N_SEQ + head * N_SEQ + q];
    *(f32x4*)(out + o) = a * (1.0f / (l * (float)NHEADS * m));
}

extern "C" void kernel_launch(void* const* d_in, const int* in_sizes, int n_in,
                              void* d_out, int out_size, void* d_ws, size_t ws_size,
                              hipStream_t stream) {
    const float* qk    = (const float*)d_in[0];
    const float* v_cls = (const float*)d_in[1];
    const float* masks = (const float*)d_in[2];
    const float* W_qk  = (const float*)d_in[3];
    const float* W_v   = (const float*)d_in[4];
    float* out = (float*)d_out;

    char* wsp = (char*)d_ws;
    size_t off = 0;
    auto allocH = [&](size_t elems) { _Float16* p = (_Float16*)(wsp + off); off += elems * 2; return p; };
    _Float16* Xh   = allocH((size_t)N_SEQ * 768);
    _Float16* Vch  = allocH((size_t)N_SEQ * 512);
    _Float16* Wqkt = allocH((size_t)1536 * 768);
    _Float16* Wvt  = allocH((size_t)512 * 512);
    _Float16* Qh   = allocH((size_t)NHEADS * N_SEQ * HD_QK);
    _Float16* Kh   = allocH((size_t)NHEADS * N_SEQ * HD_QK);
    _Float16* Vtg  = allocH((size_t)NHEADS * HD_V * N_SEQ);
    auto allocF = [&](size_t elems) { float* p = (float*)(wsp + off); off += elems * 4; return p; };
    float* Ows = allocF((size_t)2 * N_SEQ * 512);
    float* Lws = allocF((size_t)2 * NHEADS * N_SEQ);
    float* Mws = allocF((size_t)2 * NHEADS * N_SEQ);
    _Float16* Mh = allocH((size_t)N_SEQ * N_SEQ);
    const bool f16mask = ws_size >= off;

    dim3 blk(256);
    prep<<<dim3(f16mask ? 12160 : 3968), blk, 0, stream>>>(
        qk, v_cls, masks, W_qk, W_v, Xh, Vch, Mh, Wqkt, Wvt);

    proj_fused<<<dim3(16, N_SEQ / 64), blk, 0, stream>>>(
        Xh, Vch, Wqkt, Wvt, Qh, Kh, Vtg);

    if (f16mask)
        flash_attn<_Float16><<<dim3(1024), blk, 0, stream>>>(
            Qh, Kh, Vtg, Mh, Ows, Lws, Mws);
    else
        flash_attn<float><<<dim3(1024), blk, 0, stream>>>(
            Qh, Kh, Vtg, masks, Ows, Lws, Mws);

    finalize<<<dim3((N_SEQ * 512) / (256 * 4)), blk, 0, stream>>>(
        Ows, Lws, Mws, out);
}

// Round 7
// 280.085 us; speedup vs baseline: 2.1943x; 1.3115x over previous
//
#include <hip/hip_runtime.h>

typedef __attribute__((ext_vector_type(8))) _Float16 half8;
typedef __attribute__((ext_vector_type(4))) _Float16 half4;
typedef __attribute__((ext_vector_type(2))) _Float16 half2;
typedef __attribute__((ext_vector_type(2))) __fp16 fp16x2;
typedef __attribute__((ext_vector_type(4))) float f32x4;

#define N_SEQ 4096
#define HD_QK 96
#define HD_V  64
#define NHEADS 8
// Q pre-scale = (256/8)^-0.5 * log2(e) -> scores in log2 domain
#define QSCALE 0.25505545556f
#define ESHIFT 8.0f

union PKC { fp16x2 p; half2 h; };

__device__ inline half2 pk_cvt(float a, float b) {
    PKC u;
    u.p = __builtin_amdgcn_cvt_pkrtz(a, b);
    return u.h;
}

__device__ inline half8 cvt8(float4 a, float4 b) {
    half8 h;
    h[0] = (_Float16)a.x; h[1] = (_Float16)a.y; h[2] = (_Float16)a.z; h[3] = (_Float16)a.w;
    h[4] = (_Float16)b.x; h[5] = (_Float16)b.y; h[6] = (_Float16)b.z; h[7] = (_Float16)b.w;
    return h;
}

__device__ inline void cast_blk(const float* __restrict__ in, _Float16* __restrict__ out,
                                int blk, int t) {
    size_t i = ((size_t)blk * 256 + t) * 8;
    float4 a = *(const float4*)(in + i);
    float4 b = *(const float4*)(in + i + 4);
    *(half8*)(out + i) = cvt8(a, b);
}

// ---------------------------------------------------------------------------
// Prep (one launch):
//  [0,1536)     qk -> Xh f16
//  [1536,2560)  v_cls -> Vch f16
//  [2560,3712)  W_qk^T f16
//  [3712,3968)  W_v^T f16
//  [3968,12160) masks -> swizzled f16 Msw + row-sums Msum (f32 atomics)
// Msw layout (halves): chunk ((q0b*64+kb)*4 + w)*1024 + l15*64 + quad*16 + nt*4 + j
//   holds M[q0b*64 + 16nt + l15][kb*64 + 16w + 4quad + j]
// ---------------------------------------------------------------------------
__global__ __launch_bounds__(256) void prep(
    const float* __restrict__ qk, const float* __restrict__ v_cls,
    const float* __restrict__ masks, const float* __restrict__ W_qk,
    const float* __restrict__ W_v,
    _Float16* __restrict__ Xh, _Float16* __restrict__ Vch,
    _Float16* __restrict__ Msw, float* __restrict__ Msum,
    _Float16* __restrict__ Wqkt, _Float16* __restrict__ Wvt)
{
    __shared__ float tile[32][33];
    const int bx = blockIdx.x, t = threadIdx.x;
    if (bx < 1536) {
        cast_blk(qk, Xh, bx, t);
    } else if (bx < 2560) {
        cast_blk(v_cls, Vch, bx - 1536, t);
    } else if (bx < 3968) {
        const bool big = bx < 3712;
        const int id = big ? bx - 2560 : bx - 3712;
        const int nx = big ? 48 : 16;
        const int C = big ? 1536 : 512, R = big ? 768 : 512;
        const float* in = big ? W_qk : W_v;
        _Float16* out = big ? Wqkt : Wvt;
        int cx = id % nx, cy = id / nx;
        int tx = t & 31, ty = t >> 5;
        int c0 = cx * 32, r0 = cy * 32;
        for (int k = 0; k < 4; k++)
            tile[ty + 8 * k][tx] = in[(size_t)(r0 + ty + 8 * k) * C + c0 + tx];
        __syncthreads();
        for (int k = 0; k < 4; k++)
            out[(size_t)(c0 + ty + 8 * k) * R + r0 + tx] = (_Float16)tile[tx][ty + 8 * k];
    } else {
        const int m = bx - 3968;              // [0,8192), block = half mask row
        const int q = m >> 1;
        const int k0 = (m & 1) * 2048 + t * 8;
        const float* src = masks + (size_t)q * N_SEQ + k0;
        float4 a = *(const float4*)src;
        float4 b = *(const float4*)(src + 4);
        const int q0b = q >> 6, l15 = q & 15, nt = (q >> 4) & 3;
        const int kb = k0 >> 6, wsl = (k0 >> 4) & 3, qd = (k0 >> 2) & 3;
        _Float16* dst = Msw + ((size_t)(q0b * 64 + kb) * 4 + wsl) * 1024
                            + l15 * 64 + qd * 16 + nt * 4;
        half4 h0 = {(_Float16)a.x, (_Float16)a.y, (_Float16)a.z, (_Float16)a.w};
        half4 h1 = {(_Float16)b.x, (_Float16)b.y, (_Float16)b.z, (_Float16)b.w};
        *(half4*)dst = h0;
        *(half4*)(dst + 16) = h1;
        float s = (a.x + a.y) + (a.z + a.w) + (b.x + b.y) + (b.z + b.w);
        for (int off = 1; off < 64; off <<= 1) s += __shfl_xor(s, off);
        if ((t & 63) == 0) atomicAdd(&Msum[q], s);
    }
}

// ---------------------------------------------------------------------------
// Fused projection GEMM (f16 in), 128x128 tile, BK=64.
// blockIdx.x < 12: Xh@Wqkt^T (N=1536) -> Qh (xQSCALE) / Kh
// else:            Vch@Wvt^T (N=512)  -> Vtg[h][d][n]
// ---------------------------------------------------------------------------
__global__ __launch_bounds__(256) void proj_fused(
    const _Float16* __restrict__ Xh, const _Float16* __restrict__ Vch,
    const _Float16* __restrict__ Wqkt, const _Float16* __restrict__ Wvt,
    _Float16* __restrict__ Qh, _Float16* __restrict__ Kh,
    _Float16* __restrict__ Vtg)
{
    __shared__ _Float16 smem[2 * 128 * 72];   // 36.9 KB
    _Float16 (*Xs)[72] = (_Float16 (*)[72])smem;
    _Float16 (*Ws)[72] = (_Float16 (*)[72])(smem + 128 * 72);

    const int t = threadIdx.x;
    const int lane = t & 63, wv = t >> 6;
    const int quad = lane >> 4, l15 = lane & 15;
    const bool qkmode = blockIdx.x < 12;
    const int n0 = qkmode ? blockIdx.x * 128 : (blockIdx.x - 12) * 128;
    const int row0 = blockIdx.y * 128;
    const int K = qkmode ? 768 : 512;
    const _Float16* X = qkmode ? Xh : Vch;
    const _Float16* Wt = qkmode ? Wqkt : Wvt;

    const int mB = (wv & 1) * 64, nB = (wv >> 1) * 64;
    const int sr = t >> 1, sk = (t & 1) * 32;

    const f32x4 fzero = {0.f, 0.f, 0.f, 0.f};
    f32x4 acc[4][4];
    for (int i = 0; i < 4; i++)
        for (int j = 0; j < 4; j++) acc[i][j] = fzero;

    for (int k0 = 0; k0 < K; k0 += 64) {
        __syncthreads();
        {
            const _Float16* xp = X + (size_t)(row0 + sr) * K + k0 + sk;
            *(half8*)&Xs[sr][sk]      = *(const half8*)xp;
            *(half8*)&Xs[sr][sk + 8]  = *(const half8*)(xp + 8);
            *(half8*)&Xs[sr][sk + 16] = *(const half8*)(xp + 16);
            *(half8*)&Xs[sr][sk + 24] = *(const half8*)(xp + 24);
            const _Float16* wp = Wt + (size_t)(n0 + sr) * K + k0 + sk;
            *(half8*)&Ws[sr][sk]      = *(const half8*)wp;
            *(half8*)&Ws[sr][sk + 8]  = *(const half8*)(wp + 8);
            *(half8*)&Ws[sr][sk + 16] = *(const half8*)(wp + 16);
            *(half8*)&Ws[sr][sk + 24] = *(const half8*)(wp + 24);
        }
        __syncthreads();
        for (int c = 0; c < 2; c++) {
            half8 af[4], bf[4];
            for (int i = 0; i < 4; i++)
                af[i] = *(const half8*)&Xs[mB + 16 * i + l15][c * 32 + quad * 8];
            for (int j = 0; j < 4; j++)
                bf[j] = *(const half8*)&Ws[nB + 16 * j + l15][c * 32 + quad * 8];
            for (int i = 0; i < 4; i++)
                for (int j = 0; j < 4; j++)
                    acc[i][j] = __builtin_amdgcn_mfma_f32_16x16x32_f16(af[i], bf[j], acc[i][j], 0, 0, 0);
        }
    }

    __syncthreads();
    _Float16 (*Ct)[136] = (_Float16 (*)[136])smem;   // 128 x 136 = 34.8 KB
    for (int j = 0; j < 4; j++) {
        int col = n0 + nB + 16 * j + l15;
        float scl = (qkmode && col < 768) ? QSCALE : 1.0f;
        for (int i = 0; i < 4; i++)
            for (int r = 0; r < 4; r++)
                Ct[mB + 16 * i + quad * 4 + r][nB + 16 * j + l15] =
                    (_Float16)(acc[i][j][r] * scl);
    }
    __syncthreads();

    if (qkmode) {
        for (int e = 0; e < 8; e++) {
            int id = e * 256 + t;
            int row = id >> 4, cc = id & 15;
            int col = n0 + cc * 8;
            int w = col >= 768 ? 1 : 0;
            int rem = col - w * 768;
            int h = rem / 96, d = rem - h * 96;
            _Float16* dst = w ? Kh : Qh;
            *(half8*)&dst[((size_t)h * N_SEQ + row0 + row) * HD_QK + d] =
                *(const half8*)&Ct[row][cc * 8];
        }
    } else {
        for (int e = 0; e < 4; e++) {
            int id = e * 256 + t;
            int col = id >> 3, rc = id & 7;
            int c = n0 + col;
            int h = c >> 6, d = c & 63;
            half8 v0, v1;
            for (int k = 0; k < 8; k++) {
                v0[k] = Ct[rc * 16 + k][col];
                v1[k] = Ct[rc * 16 + 8 + k][col];
            }
            _Float16* dst = &Vtg[((size_t)h * HD_V + d) * N_SEQ + row0 + rc * 16];
            *(half8*)dst = v0;
            *(half8*)(dst + 8) = v1;
        }
    }
}

// ---------------------------------------------------------------------------
// Flash attention: key-sliced waves, split-K z=3 (grid 1536 = 2 exact rounds
// at 3 WG/CU), q0-major XCD pinning (bx%8 == q0b%8 -> mask slice L2-resident).
// Swizzled f16 masks: 2 contiguous 16B loads/iter. No msum (precomputed).
// p = exp2(s'-8) exact shift; partials (O f16, l f32) to ws.
// ---------------------------------------------------------------------------
__global__ __launch_bounds__(256, 3) void flash_attn(
    const _Float16* __restrict__ Qh, const _Float16* __restrict__ Kh,
    const _Float16* __restrict__ Vtg, const _Float16* __restrict__ Msw,
    _Float16* __restrict__ Owsh, float* __restrict__ Lws)
{
    __shared__ __align__(16) float Ob[2][64][68];
    __shared__ float Lb[2][64];

    const int t = threadIdx.x;
    const int lane = t & 63, w = t >> 6;
    const int quad = lane >> 4, l15 = lane & 15;
    const int bx = blockIdx.x;
    const int q0b = bx & 63;
    const int hz = bx >> 6;
    const int head = hz & 7;
    const int z = hz >> 3;
    const int q0 = q0b * 64;
    const int kb0 = 21 * z, kbE = (z == 2) ? 64 : kb0 + 21;

    half8 qf[3][4];
    for (int nt = 0; nt < 4; nt++) {
        const _Float16* qp = Qh + ((size_t)head * N_SEQ + q0 + 16 * nt + l15) * HD_QK + 8 * quad;
        for (int c = 0; c < 3; c++)
            qf[c][nt] = *(const half8*)(qp + 32 * c);
    }

    const _Float16* kbase = Kh + ((size_t)head * N_SEQ + 16 * w + l15) * HD_QK + 8 * quad;
    const _Float16* vbase = Vtg + ((size_t)head * HD_V + l15) * N_SEQ + 16 * w + 4 * quad;
    const _Float16* mbase = Msw + ((size_t)(q0b * 64 + kb0) * 4 + w) * 1024
                                + (l15 * 4 + quad) * 16;

    const f32x4 fzero = {0.f, 0.f, 0.f, 0.f};
    f32x4 oacc[4][4];
    for (int nt = 0; nt < 4; nt++)
        for (int v = 0; v < 4; v++) oacc[nt][v] = fzero;
    float lsum[4] = {0.f, 0.f, 0.f, 0.f};

    half8 kf[3];
    half4 vf[4];
    half8 m01, m23;
    {
        const _Float16* kp = kbase + (size_t)kb0 * 64 * HD_QK;
        for (int c = 0; c < 3; c++) kf[c] = *(const half8*)(kp + 32 * c);
        const _Float16* vp = vbase + kb0 * 64;
        for (int v = 0; v < 4; v++) vf[v] = *(const half4*)(vp + (size_t)(16 * v) * N_SEQ);
        m01 = *(const half8*)mbase;
        m23 = *(const half8*)(mbase + 8);
    }

    for (int kb = kb0; kb < kbE; kb++) {
        const int kn = (kb + 1 < kbE) ? kb + 1 : kb;

        // S^T = K Q^T
        f32x4 sT[4];
        for (int nt = 0; nt < 4; nt++) sT[nt] = fzero;
        for (int c = 0; c < 3; c++)
            for (int nt = 0; nt < 4; nt++)
                sT[nt] = __builtin_amdgcn_mfma_f32_16x16x32_f16(kf[c], qf[c][nt], sT[nt], 0, 0, 0);
        {
            const _Float16* kp = kbase + (size_t)kn * 64 * HD_QK;
            for (int c = 0; c < 3; c++) kf[c] = *(const half8*)(kp + 32 * c);
        }

        // p = exp2(s-8); lsum; af = f16(p) * mask (packed f16 math)
        half4 af[4];
        {
            half2 mh[8];
            for (int i = 0; i < 4; i++) {
                mh[i]     = half2{m01[2 * i], m01[2 * i + 1]};
                mh[4 + i] = half2{m23[2 * i], m23[2 * i + 1]};
            }
            for (int nt = 0; nt < 4; nt++) {
                float p0 = exp2f(sT[nt][0] - ESHIFT);
                float p1 = exp2f(sT[nt][1] - ESHIFT);
                float p2 = exp2f(sT[nt][2] - ESHIFT);
                float p3 = exp2f(sT[nt][3] - ESHIFT);
                lsum[nt] += (p0 + p1) + (p2 + p3);
                half2 lo = pk_cvt(p0, p1) * mh[2 * nt];
                half2 hi = pk_cvt(p2, p3) * mh[2 * nt + 1];
                af[nt] = half4{lo[0], lo[1], hi[0], hi[1]};
            }
        }
        {
            const _Float16* mp = mbase + (size_t)(kn - kb0) * 4096;
            m01 = *(const half8*)mp;
            m23 = *(const half8*)(mp + 8);
        }

        // O += P V
        for (int nt = 0; nt < 4; nt++)
            for (int v = 0; v < 4; v++)
                oacc[nt][v] = __builtin_amdgcn_mfma_f32_16x16x16f16(af[nt], vf[v], oacc[nt][v], 0, 0, 0);
        {
            const _Float16* vp = vbase + kn * 64;
            for (int v = 0; v < 4; v++) vf[v] = *(const half4*)(vp + (size_t)(16 * v) * N_SEQ);
        }
    }

    for (int nt = 0; nt < 4; nt++) {
        lsum[nt] += __shfl_xor(lsum[nt], 16);
        lsum[nt] += __shfl_xor(lsum[nt], 32);
    }

    if (w & 1) {
        for (int nt = 0; nt < 4; nt++) {
            for (int v = 0; v < 4; v++)
                for (int r = 0; r < 4; r++)
                    Ob[w >> 1][16 * nt + 4 * quad + r][16 * v + l15] = oacc[nt][v][r];
            if (quad == 0) Lb[w >> 1][16 * nt + l15] = lsum[nt];
        }
    }
    __syncthreads();
    if (!(w & 1)) {
        for (int nt = 0; nt < 4; nt++) {
            for (int v = 0; v < 4; v++)
                for (int r = 0; r < 4; r++)
                    Ob[w >> 1][16 * nt + 4 * quad + r][16 * v + l15] += oacc[nt][v][r];
            if (quad == 0) Lb[w >> 1][16 * nt + l15] += lsum[nt];
        }
    }
    __syncthreads();

    {
        int row = t >> 2, c0 = (t & 3) * 16;
        _Float16* obase = Owsh + (size_t)z * N_SEQ * 512 + (size_t)(q0 + row) * 512
                          + head * HD_V + c0;
        for (int g = 0; g < 2; g++) {
            half8 h;
            for (int j = 0; j < 8; j++)
                h[j] = (_Float16)(Ob[0][row][c0 + 8 * g + j] + Ob[1][row][c0 + 8 * g + j]);
            *(half8*)(obase + 8 * g) = h;
        }
        if (t < 64)
            Lws[((size_t)z * NHEADS + head) * N_SEQ + q0 + t] = Lb[0][t] + Lb[1][t];
    }
}

// ---------------------------------------------------------------------------
// Finalize: out = sum_z O_z / (sum_z l_z * H * Msum[q])
// ---------------------------------------------------------------------------
__global__ __launch_bounds__(256) void finalize(
    const _Float16* __restrict__ Owsh, const float* __restrict__ Lws,
    const float* __restrict__ Msum, float* __restrict__ out)
{
    const size_t ZSTR = (size_t)N_SEQ * 512;
    size_t o = ((size_t)blockIdx.x * 256 + threadIdx.x) * 8;
    int q = (int)(o >> 9);
    int head = (int)((o & 511) >> 6);
    half8 p0 = *(const half8*)(Owsh + o);
    half8 p1 = *(const half8*)(Owsh + ZSTR + o);
    half8 p2 = *(const half8*)(Owsh + 2 * ZSTR + o);
    float l = Lws[(size_t)head * N_SEQ + q]
            + Lws[((size_t)NHEADS + head) * N_SEQ + q]
            + Lws[((size_t)2 * NHEADS + head) * N_SEQ + q];
    float inv = 1.0f / (l * (float)NHEADS * Msum[q]);
    float4 r0, r1;
    r0.x = ((float)p0[0] + (float)p1[0] + (float)p2[0]) * inv;
    r0.y = ((float)p0[1] + (float)p1[1] + (float)p2[1]) * inv;
    r0.z = ((float)p0[2] + (float)p1[2] + (float)p2[2]) * inv;
    r0.w = ((float)p0[3] + (float)p1[3] + (float)p2[3]) * inv;
    r1.x = ((float)p0[4] + (float)p1[4] + (float)p2[4]) * inv;
    r1.y = ((float)p0[5] + (float)p1[5] + (float)p2[5]) * inv;
    r1.z = ((float)p0[6] + (float)p1[6] + (float)p2[6]) * inv;
    r1.w = ((float)p0[7] + (float)p1[7] + (float)p2[7]) * inv;
    *(float4*)(out + o) = r0;
    *(float4*)(out + o + 4) = r1;
}

extern "C" void kernel_launch(void* const* d_in, const int* in_sizes, int n_in,
                              void* d_out, int out_size, void* d_ws, size_t ws_size,
                              hipStream_t stream) {
    const float* qk    = (const float*)d_in[0];
    const float* v_cls = (const float*)d_in[1];
    const float* masks = (const float*)d_in[2];
    const float* W_qk  = (const float*)d_in[3];
    const float* W_v   = (const float*)d_in[4];
    float* out = (float*)d_out;

    char* wsp = (char*)d_ws;
    // region0 [0, 13 MB): prep-stage buffers, later aliased by Owsh (12.6 MB)
    _Float16* Xh   = (_Float16*)(wsp);                         // 6.0 MB
    _Float16* Vch  = (_Float16*)(wsp + (size_t)6291456);       // 4.0 MB
    _Float16* Wqkt = (_Float16*)(wsp + (size_t)10485760);      // 2.25 MB
    _Float16* Wvt  = (_Float16*)(wsp + (size_t)12845056);      // 0.5 MB
    _Float16* Owsh = (_Float16*)(wsp);                         // 3*4096*512*2 = 12.58 MB
    size_t off = 13631488;                                     // 13 MB
    auto allocB = [&](size_t bytes) { char* p = wsp + off; off += (bytes + 255) & ~(size_t)255; return p; };
    _Float16* Qh   = (_Float16*)allocB((size_t)NHEADS * N_SEQ * HD_QK * 2);
    _Float16* Kh   = (_Float16*)allocB((size_t)NHEADS * N_SEQ * HD_QK * 2);
    _Float16* Vtg  = (_Float16*)allocB((size_t)NHEADS * HD_V * N_SEQ * 2);
    _Float16* Msw  = (_Float16*)allocB((size_t)N_SEQ * N_SEQ * 2);
    float*    Msum = (float*)allocB((size_t)N_SEQ * 4);
    float*    Lws  = (float*)allocB((size_t)3 * NHEADS * N_SEQ * 4);
    (void)ws_size;

    dim3 blk(256);
    (void)hipMemsetAsync(Msum, 0, N_SEQ * sizeof(float), stream);
    prep<<<dim3(12160), blk, 0, stream>>>(
        qk, v_cls, masks, W_qk, W_v, Xh, Vch, Msw, Msum, Wqkt, Wvt);

    proj_fused<<<dim3(16, N_SEQ / 128), blk, 0, stream>>>(
        Xh, Vch, Wqkt, Wvt, Qh, Kh, Vtg);

    flash_attn<<<dim3(1536), blk, 0, stream>>>(
        Qh, Kh, Vtg, Msw, Owsh, Lws);

    finalize<<<dim3((N_SEQ * 512) / (256 * 8)), blk, 0, stream>>>(
        Owsh, Lws, Msum, out);
}